// Round 7
// baseline (166.580 us; speedup 1.0000x reference)
//
#include <hip/hip_runtime.h>
#include <hip/hip_fp16.h>

#define BATCH 8192
#define FDIM  512
#define NTREE 64
#define NODES 63
#define ODIM  128
#define NJP   4096            // padded node-col space
#define K2    4096            // leaf K: k = t*64 + l
#define TPG   8               // tree-pair groups (grid.y); 4 tree-pairs each

typedef _Float16 f16;
typedef _Float16 f16x2 __attribute__((ext_vector_type(2)));
typedef _Float16 f16x4 __attribute__((ext_vector_type(4)));
typedef _Float16 f16x8 __attribute__((ext_vector_type(8)));
typedef float    f32x4 __attribute__((ext_vector_type(4)));

// ---------------- workspace layout (bytes) ----------------
// Fragment-ordered operands (16B/lane chunks). v-index (16B units):
//   xhF : bx*8192 + k0*1024 + rg*128 + ks*64 + lane   (rg = batch-16-group)
//   wnhF: tp*8192 + k0*1024 + cg*128 + ks*64 + lane   (cg = permuted-node-row>>4)
//         node n of tree t placed at in-tree ROW rho(n)  [fold-friendly permutation]
//   wltF: tp*2048 + h*1024 + to*128 + ks*64 + lane    (l = (ks*4+lane>>4)*8+e)
//   bnF : [tree][rho(n)] f32  (bias in the same permuted row order)
#define XH_OFF   0
#define XH_SZ    ((size_t)BATCH*FDIM*2)        // 8.39 MB
#define WNH_OFF  (XH_OFF + XH_SZ)
#define WNH_SZ   ((size_t)NJP*FDIM*2)          // 4.19 MB
#define WLT_OFF  (WNH_OFF + WNH_SZ)
#define WLT_SZ   ((size_t)ODIM*K2*2)           // 1.05 MB
#define BNF_OFF  (WLT_OFF + WLT_SZ)
#define BNF_SZ   ((size_t)NTREE*64*4)          // 16 KB
#define PS_OFF   (BNF_OFF + BNF_SZ)
#define PS_SZ    ((size_t)TPG*BATCH*ODIM*4)    // 33.6 MB  f32 partials per tp-group
#define WS_NEEDED (PS_OFF + PS_SZ)             // 47.2 MB

__device__ __forceinline__ float smooth_step_f(float t) {
    float tc = fminf(fmaxf(t, -0.5f), 0.5f);
    return fmaf(tc, fmaf(-2.0f * tc, tc, 1.5f), 0.5f);
}

// fold-friendly node-row permutation (in-tree node n -> row 0..63):
//  rows  0..14 : nodes 0..14 (levels 0-3) -> broadcast via 15 shfls
//  row     15  : pad (node 63)
//  rows 16..31 : level-4 nodes arranged so lane q holds exactly
//                {15+2q, 16+2q, 23+2q, 24+2q} in regs r0..r3 (tile 1)
//  rows 32..47 : level-5 nodes 31+4q+j at (q, r=j)   (tile 2)
//  rows 48..63 : level-5 nodes 47+4q+j at (q, r=j)   (tile 3)
__device__ __forceinline__ int rho(int n) {
    if (n < 15)  return n;
    if (n == 63) return 15;
    if (n < 31) { int m = n - 15; int hi = (m >= 8) ? 1 : 0; int mm = m - hi * 8;
                  return 16 + (mm >> 1) * 4 + (mm & 1) + hi * 2; }
    return n + 1;
}

// ---------------- prep: fragment-ordered operand buffers + bnF ----------------
// blocks [0,512): xhF ; [512,768): wnhF (rho-permuted rows) ; [768,832): wltF ;
// block 832: bnF (bias transpose into permuted row order)
__global__ __launch_bounds__(256)
void prep_kernel(const float* __restrict__ x, const float* __restrict__ wn,
                 const float* __restrict__ wl, const float* __restrict__ bn,
                 f16* __restrict__ xf, f16* __restrict__ wnf, f16* __restrict__ wlf,
                 float* __restrict__ bnf)
{
    const int bid = blockIdx.x, tid = threadIdx.x;
    if (bid == 832) {                      // ---- bnF[t][rho(n)] = bn[n][t]
        #pragma unroll
        for (int i = 0; i < 16; ++i) {
            int idx = tid * 16 + i;
            int n = idx & 63, t = idx >> 6;
            bnf[t * 64 + rho(n)] = (n < NODES) ? bn[n * NTREE + t] : 0.0f;
        }
        return;
    }
    if (bid < 512) {                       // ---- xhF
        const int bx = bid >> 3, k0 = bid & 7;
        f16* dst = xf + ((size_t)bx * 8192 + (size_t)k0 * 1024) * 8;
        #pragma unroll
        for (int c = 0; c < 4; ++c) {
            int fid  = c * 256 + tid;
            int lane = fid & 63, ks = (fid >> 6) & 1, rg = (fid >> 7) & 7;
            int row  = bx * 128 + rg * 16 + (lane & 15);
            int k    = k0 * 64 + (ks * 4 + (lane >> 4)) * 8;
            const float* s = x + (size_t)row * FDIM + k;
            float4 a = *(const float4*)s, b = *(const float4*)(s + 4);
            f16x8 v = { (f16)a.x, (f16)a.y, (f16)a.z, (f16)a.w,
                        (f16)b.x, (f16)b.y, (f16)b.z, (f16)b.w };
            *(f16x8*)(dst + (size_t)fid * 8) = v;
        }
    } else if (bid < 768) {                // ---- wnhF: float4 over t, rho-permuted rows
        const int id = bid - 512;          // 0..255
        const int t0 = (id >> 4) * 4;      // 16 t-quads
        const int n  = tid & 63;           // 0..63 (63 = pad)
        const int k8 = (id & 15) * 4 + (tid >> 6);   // 0..63 (k = k8*8+e)
        const int rr = rho(n);
        float4 q[8];
        if (n != NODES) {
            #pragma unroll
            for (int e = 0; e < 8; ++e)
                q[e] = *(const float4*)(wn + ((size_t)n * FDIM + k8 * 8 + e) * NTREE + t0);
        }
        #pragma unroll
        for (int j = 0; j < 4; ++j) {
            int t  = t0 + j;
            int tp = t >> 1;
            int cg = (t & 1) * 4 + (rr >> 4);
            size_t chunk = (size_t)tp * 8192 + (size_t)(k8 >> 3) * 1024 + cg * 128
                         + ((k8 >> 2) & 1) * 64 + (k8 & 3) * 16 + (rr & 15);
            f16x8 v;
            if (n == NODES) {
                #pragma unroll
                for (int e = 0; e < 8; ++e) v[e] = (f16)0.0f;
            } else {
                const float* qf = (const float*)q;
                #pragma unroll
                for (int e = 0; e < 8; ++e) v[e] = (f16)qf[e * 4 + j];
            }
            *(f16x8*)(wnf + chunk * 8) = v;
        }
    } else {                               // ---- wltF: float4 over t, reg transpose
        const int id = bid - 768;          // 0..63
        const int t0 = (id >> 2) * 4;
        const int o  = tid & 127;
        const int l8 = (id & 3) * 2 + (tid >> 7);    // 0..7 (l = l8*8+e)
        float4 q[8];
        #pragma unroll
        for (int e = 0; e < 8; ++e)
            q[e] = *(const float4*)(wl + ((size_t)(l8 * 8 + e) * ODIM + o) * NTREE + t0);
        #pragma unroll
        for (int j = 0; j < 4; ++j) {
            int t  = t0 + j;
            int tp = t >> 1, h = t & 1;
            size_t chunk = (size_t)tp * 2048 + (size_t)h * 1024 + (o >> 4) * 128
                         + (l8 >> 2) * 64 + (l8 & 3) * 16 + (o & 15);
            const float* qf = (const float*)q;
            f16x8 v;
            #pragma unroll
            for (int e = 0; e < 8; ++e) v[e] = (f16)qf[e * 4 + j];
            *(f16x8*)(wlf + chunk * 8) = v;
        }
    }
}

// ---------------- fused: ZERO-barrier, ZERO-LDS pipeline ----------------
// Swapped node GEMM: mfma(Wn_frag, x_frag) -> gates[node-row][batch-col]; each
// lane holds all 64 permuted gate rows for its batch column -> fold is 15 in-wave
// shfl broadcasts + constant-indexed VALU (T12: reduction axis made lane-local).
// P emerges directly in leaf-A fragment layout (lane q owns leaves 8q..8q+7 and
// 32+8q..+7 = the MFMA k-chunks) -> leaf GEMM from registers. No __syncthreads.
// grid (64 rowblks, 8 tpgroups); wave = 32 batch x 128 node-cols (both trees).
__global__ __launch_bounds__(256, 2)
void fused_tree(const f16* __restrict__ xhF, const f16* __restrict__ wnhF,
                const float* __restrict__ bnF, const f16* __restrict__ wltF,
                float* __restrict__ partial)
{
    const int tid  = threadIdx.x;
    const int lane = tid & 63;
    const int w    = tid >> 6;                // 0..3: batch band of 32
    const int q    = lane >> 4;               // 0..3
    const int c    = lane & 15;               // batch-within-16
    const int tpg  = blockIdx.y;

    const f16x8* __restrict__ xv = (const f16x8*)xhF;
    const f16x8* __restrict__ wv = (const f16x8*)wnhF;
    const f16x8* __restrict__ lv = (const f16x8*)wltF;
    const size_t xb = (size_t)blockIdx.x * 8192 + (size_t)(w * 2) * 128 + lane;

    f32x4 lacc[2][8] = {};                    // [tb][to], persists over tree-pairs

    for (int tpi = 0; tpi < 4; ++tpi) {
        const int tp = tpg * 4 + tpi;

        // ---- node GEMM: gates = Wn^T x : C[node-row][batch], no LDS, no barriers
        const size_t wb = (size_t)tp * 8192 + lane;
        f32x4 acc[8][2] = {};                 // [tn(node 16-group)][tb]
        #pragma unroll 2
        for (int k0 = 0; k0 < 8; ++k0) {
            #pragma unroll
            for (int ks = 0; ks < 2; ++ks) {
                f16x8 xf0 = xv[xb + k0 * 1024 + 0 * 128 + ks * 64];
                f16x8 xf1 = xv[xb + k0 * 1024 + 1 * 128 + ks * 64];
                #pragma unroll
                for (int tn = 0; tn < 8; ++tn) {
                    f16x8 afr = wv[wb + k0 * 1024 + tn * 128 + ks * 64];
                    acc[tn][0] = __builtin_amdgcn_mfma_f32_16x16x32_f16(afr, xf0, acc[tn][0], 0, 0, 0);
                    acc[tn][1] = __builtin_amdgcn_mfma_f32_16x16x32_f16(afr, xf1, acc[tn][1], 0, 0, 0);
                }
            }
        }

        // ---- gate epilogue in-register: bias + smooth_step
        #pragma unroll
        for (int tn = 0; tn < 8; ++tn) {
            int tree = tp * 2 + (tn >> 2);
            f32x4 bv = *(const f32x4*)(bnF + tree * 64 + (tn & 3) * 16 + q * 4);
            #pragma unroll
            for (int tb = 0; tb < 2; ++tb)
                #pragma unroll
                for (int r = 0; r < 4; ++r)
                    acc[tn][tb][r] = smooth_step_f(acc[tn][tb][r] + bv[r]);
        }

        // ---- fold in-register per (tree wt, batch-tile tb) -> P fragments
        f16x8 pf[2][2][2];                    // [wt][tb][ks]
        #pragma unroll
        for (int wt = 0; wt < 2; ++wt) {
            #pragma unroll
            for (int tb = 0; tb < 2; ++tb) {
                const f32x4 s0 = acc[wt * 4 + 0][tb];   // top gates (rows 0..14)
                const f32x4 s1 = acc[wt * 4 + 1][tb];   // l4 gates {15+2q,16+2q,23+2q,24+2q}
                const f32x4 s2 = acc[wt * 4 + 2][tb];   // l5 gates 31+4q+j
                const f32x4 s3 = acc[wt * 4 + 3][tb];   // l5 gates 47+4q+j
                // broadcast the 15 shared top gates (reg index compile-time)
                float t0  = __shfl(s0[0], c);
                float t1  = __shfl(s0[1], c);
                float t2  = __shfl(s0[2], c);
                float t3  = __shfl(s0[3], c);
                float t4  = __shfl(s0[0], c + 16);
                float t5  = __shfl(s0[1], c + 16);
                float t6  = __shfl(s0[2], c + 16);
                float t7  = __shfl(s0[3], c + 16);
                float t8  = __shfl(s0[0], c + 32);
                float t9  = __shfl(s0[1], c + 32);
                float t10 = __shfl(s0[2], c + 32);
                float t11 = __shfl(s0[3], c + 32);
                float t12 = __shfl(s0[0], c + 48);
                float t13 = __shfl(s0[1], c + 48);
                float t14 = __shfl(s0[2], c + 48);
                // entering-products down to level 3 (all constant-indexed)
                float P1 = t0,        P2 = 1.0f - t0;
                float P3 = P1 * t1,   P4 = P1 - P3, P5 = P2 * t2,  P6 = P2 - P5;
                float P7 = P3 * t3,   P8 = P3 - P7, P9 = P4 * t4,  P10 = P4 - P9;
                float P11 = P5 * t5,  P12 = P5 - P11, P13 = P6 * t6, P14 = P6 - P13;
                // per-lane select of its two level-3 subtrees (cndmask, no scratch)
                int qa = q & 1, qb = q & 2;
                float PA  = qb ? (qa ? P10 : P9 ) : (qa ? P8  : P7 );
                float sga = qb ? (qa ? t10 : t9 ) : (qa ? t8  : t7 );   // gate(7+q)
                float PB  = qb ? (qa ? P14 : P13) : (qa ? P12 : P11);
                float sgb = qb ? (qa ? t14 : t13) : (qa ? t12 : t11);   // gate(11+q)
                float E0 = PA * sga, E1 = PA - E0, E2 = PB * sgb, E3 = PB - E2;
                // level-4 step (gates local in s1)
                float F0 = E0 * s1[0], F1 = E0 - F0, F2 = E1 * s1[1], F3 = E1 - F2;
                float G0 = E2 * s1[2], G1 = E2 - G0, G2 = E3 * s1[3], G3 = E3 - G2;
                // level-5 step -> 16 leaf probs (leaves 8q+j and 32+8q+j)
                float L0 = F0 * s2[0], L1 = F0 - L0, L2 = F1 * s2[1], L3 = F1 - L2;
                float L4 = F2 * s2[2], L5 = F2 - L4, L6 = F3 * s2[3], L7 = F3 - L6;
                float M0 = G0 * s3[0], M1 = G0 - M0, M2 = G1 * s3[1], M3 = G1 - M2;
                float M4 = G2 * s3[2], M5 = G2 - M4, M6 = G3 * s3[3], M7 = G3 - M6;
                f16x8 pa = { (f16)L0, (f16)L1, (f16)L2, (f16)L3,
                             (f16)L4, (f16)L5, (f16)L6, (f16)L7 };
                f16x8 pb = { (f16)M0, (f16)M1, (f16)M2, (f16)M3,
                             (f16)M4, (f16)M5, (f16)M6, (f16)M7 };
                pf[wt][tb][0] = pa;
                pf[wt][tb][1] = pb;
            }
        }

        // ---- leaf GEMM: P from registers, Wl fragment-direct from L2
        const size_t lb = (size_t)tp * 2048 + lane;
        #pragma unroll
        for (int wt = 0; wt < 2; ++wt) {
            #pragma unroll
            for (int ks = 0; ks < 2; ++ks) {
                #pragma unroll
                for (int to = 0; to < 8; ++to) {
                    f16x8 blf = lv[lb + wt * 1024 + to * 128 + ks * 64];
                    lacc[0][to] = __builtin_amdgcn_mfma_f32_16x16x32_f16(pf[wt][0][ks], blf, lacc[0][to], 0, 0, 0);
                    lacc[1][to] = __builtin_amdgcn_mfma_f32_16x16x32_f16(pf[wt][1][ks], blf, lacc[1][to], 0, 0, 0);
                }
            }
        }
    }

    // ---- write f32 partial for this tp-group (streamed, no atomics, no fences)
    float* dst = partial + (size_t)tpg * BATCH * ODIM;
    const int row0 = blockIdx.x * 128 + w * 32;
    #pragma unroll
    for (int tb = 0; tb < 2; ++tb) {
        #pragma unroll
        for (int to = 0; to < 8; ++to) {
            #pragma unroll
            for (int r = 0; r < 4; ++r) {
                int row = row0 + tb * 16 + q * 4 + r;
                dst[(size_t)row * ODIM + to * 16 + c] = lacc[tb][to][r];
            }
        }
    }
}

// ---------------- split reduce over TPG partials ----------------
__global__ void reduce_kernel(const float* __restrict__ partial, float* __restrict__ out) {
    size_t i = ((size_t)blockIdx.x * blockDim.x + threadIdx.x) * 4;
    f32x4 a = *(const f32x4*)(partial + i);
    #pragma unroll
    for (int k = 1; k < TPG; ++k)
        a += *(const f32x4*)(partial + (size_t)k * BATCH * ODIM + i);
    *(f32x4*)(out + i) = a;
}

// ---------------- fallback (round-1 proven kernel) ----------------
#define ROWS 8
__global__ __launch_bounds__(256, 2)
void soft_tree_fallback(const float* __restrict__ x, const float* __restrict__ Wn,
                        const float* __restrict__ bn, const float* __restrict__ Wl,
                        float* __restrict__ out)
{
    __shared__ __half s_lds[ROWS][NODES][NTREE];
    const int lane = threadIdx.x & 63;
    const int w    = threadIdx.x >> 6;
    const long row0 = (long)blockIdx.x * ROWS;
    for (int n = w; n < NODES; n += 4) {
        const float* wp = Wn + ((long)n * FDIM) * NTREE + lane;
        const float* xp = x + row0 * FDIM;
        float acc[ROWS];
        #pragma unroll
        for (int r = 0; r < ROWS; ++r) acc[r] = 0.0f;
        #pragma unroll 8
        for (int f = 0; f < FDIM; ++f) {
            float wv = wp[(long)f * NTREE];
            #pragma unroll
            for (int r = 0; r < ROWS; ++r)
                acc[r] = fmaf(xp[r * FDIM + f], wv, acc[r]);
        }
        float bias = bn[n * NTREE + lane];
        #pragma unroll
        for (int r = 0; r < ROWS; ++r)
            s_lds[r][n][lane] = __float2half(smooth_step_f(acc[r] + bias));
    }
    __syncthreads();
    const int r0 = w * 2, r1 = w * 2 + 1;
    float pr0[64], pr1[64];
    {
        pr0[0] = 1.0f; pr1[0] = 1.0f;
        int base = 0;
        #pragma unroll
        for (int lvl = 0; lvl < 6; ++lvl) {
            const int width = 1 << lvl;
            #pragma unroll
            for (int i = width - 1; i >= 0; --i) {
                float sa = __half2float(s_lds[r0][base + i][lane]);
                float sb = __half2float(s_lds[r1][base + i][lane]);
                float pa = pr0[i], pb = pr1[i];
                pr0[2 * i] = pa * sa; pr0[2 * i + 1] = pa * (1.0f - sa);
                pr1[2 * i] = pb * sb; pr1[2 * i + 1] = pb * (1.0f - sb);
            }
            base += width;
        }
    }
    for (int o = 0; o < ODIM; ++o) {
        const float* wlp = Wl + (long)o * NTREE + lane;
        float c0 = 0.0f, c1 = 0.0f;
        #pragma unroll
        for (int l = 0; l < 64; ++l) {
            float wv = wlp[(long)l * (ODIM * NTREE)];
            c0 = fmaf(pr0[l], wv, c0);
            c1 = fmaf(pr1[l], wv, c1);
        }
        #pragma unroll
        for (int off = 32; off > 0; off >>= 1) {
            c0 += __shfl_xor(c0, off, 64);
            c1 += __shfl_xor(c1, off, 64);
        }
        if (lane == 0) {
            out[(row0 + r0) * ODIM + o] = c0;
            out[(row0 + r1) * ODIM + o] = c1;
        }
    }
}

extern "C" void kernel_launch(void* const* d_in, const int* in_sizes, int n_in,
                              void* d_out, int out_size, void* d_ws, size_t ws_size,
                              hipStream_t stream) {
    const float* x  = (const float*)d_in[0];
    const float* Wn = (const float*)d_in[1];
    const float* bn = (const float*)d_in[2];
    const float* Wl = (const float*)d_in[3];
    float* out = (float*)d_out;

    if (ws_size < WS_NEEDED) {
        soft_tree_fallback<<<BATCH / ROWS, 256, 0, stream>>>(x, Wn, bn, Wl, out);
        return;
    }

    f16*   xh  = (f16*)((char*)d_ws + XH_OFF);
    f16*   wnh = (f16*)((char*)d_ws + WNH_OFF);
    f16*   wlt = (f16*)((char*)d_ws + WLT_OFF);
    float* bnf = (float*)((char*)d_ws + BNF_OFF);
    float* ps  = (float*)((char*)d_ws + PS_OFF);

    prep_kernel<<<833, 256, 0, stream>>>(x, Wn, Wl, bn, xh, wnh, wlt, bnf);
    fused_tree<<<dim3(BATCH / 128, TPG), 256, 0, stream>>>(xh, wnh, bnf, wlt, ps);
    reduce_kernel<<<(BATCH * ODIM) / (256 * 4), 256, 0, stream>>>(ps, out);
}